// Round 1
// baseline (656.919 us; speedup 1.0000x reference)
//
#include <hip/hip_runtime.h>
#include <stdint.h>

#define T_TOK 2048
#define DIM   1024
#define HID   4096
#define NEXP  8

typedef __attribute__((ext_vector_type(8))) short  short8;
typedef __attribute__((ext_vector_type(4))) short  short4v;
typedef __attribute__((ext_vector_type(4))) float  floatx4;
typedef __attribute__((ext_vector_type(4))) int    intx4;

__device__ __forceinline__ ushort f2bf(float f) {
    union { float f; uint32_t i; } v; v.f = f;
    uint32_t r = v.i + 0x7FFFu + ((v.i >> 16) & 1u);
    return (ushort)(r >> 16);
}
__device__ __forceinline__ float gelu_exact(float x) {
    return 0.5f * x * (1.0f + erff(x * 0.70710678118654752f));
}
// async global->LDS DMA, 16B per lane. LDS dest must be wave-uniform base
// (lane i lands at base + i*16); global source is per-lane.
__device__ __forceinline__ void glds16(const ushort* g, ushort* lds) {
    __builtin_amdgcn_global_load_lds(
        (const __attribute__((address_space(1))) unsigned int*)g,
        (__attribute__((address_space(3))) unsigned int*)lds, 16, 0, 0);
}

// ------------------------------------------------- x (fp32) -> bf16 Xb
__global__ __launch_bounds__(256) void cast_x_kernel(
    const float* __restrict__ x, ushort* __restrict__ Xb)
{
    int i = (blockIdx.x * 256 + threadIdx.x) * 8;
    floatx4 a = *(const floatx4*)(x + i);
    floatx4 b = *(const floatx4*)(x + i + 4);
    uint32_t o[4];
    o[0] = (uint32_t)f2bf(a[0]) | ((uint32_t)f2bf(a[1]) << 16);
    o[1] = (uint32_t)f2bf(a[2]) | ((uint32_t)f2bf(a[3]) << 16);
    o[2] = (uint32_t)f2bf(b[0]) | ((uint32_t)f2bf(b[1]) << 16);
    o[3] = (uint32_t)f2bf(b[2]) | ((uint32_t)f2bf(b[3]) << 16);
    *(intx4*)(Xb + i) = *(const intx4*)o;
}

// ------------------------------------------------- W (fp32 [R][C]) -> bf16 [C][R]
// Per expert: out[c][r] = bf16(in[r][c]). 64x64 LDS tile, coalesced both sides.
__global__ __launch_bounds__(256) void transpose_cast_kernel(
    const float* __restrict__ in, ushort* __restrict__ out, int R, int C)
{
    __shared__ float tile[64][65];
    int e = blockIdx.z;
    int rb = blockIdx.y * 64, cb = blockIdx.x * 64;
    const float* ip = in + (size_t)e * R * C;
    ushort* op = out + (size_t)e * R * C;
    int t = threadIdx.x;
    int tr = t >> 4, tc4 = (t & 15) * 4;
#pragma unroll
    for (int i = 0; i < 4; i++) {
        int r = i * 16 + tr;
        floatx4 v = *(const floatx4*)(ip + (size_t)(rb + r) * C + cb + tc4);
        tile[r][tc4] = v[0]; tile[r][tc4 + 1] = v[1];
        tile[r][tc4 + 2] = v[2]; tile[r][tc4 + 3] = v[3];
    }
    __syncthreads();
    int cc = t >> 2, rseg = (t & 3) * 16;
#pragma unroll
    for (int s = 0; s < 2; s++) {
        ushort o[8];
#pragma unroll
        for (int j = 0; j < 8; j++) o[j] = f2bf(tile[rseg + s * 8 + j][cc]);
        *(intx4*)(op + (size_t)(cb + cc) * R + rb + rseg + s * 8) = *(const intx4*)o;
    }
}

// ------------------------------------------------- router (fp32)
__global__ __launch_bounds__(256) void router_kernel(
    const float* __restrict__ x, const float* __restrict__ Wr,
    const float* __restrict__ br, int* __restrict__ counts,
    int* __restrict__ tlist, float* __restrict__ wlist)
{
    int wv = threadIdx.x >> 6, l = threadIdx.x & 63;
    int t = blockIdx.x * 4 + wv;
    float acc[NEXP];
#pragma unroll
    for (int e = 0; e < NEXP; e++) acc[e] = 0.f;
    const float* xr = x + (size_t)t * DIM;
    for (int d = l; d < DIM; d += 64) {
        float xv = xr[d];
        floatx4 w0 = *(const floatx4*)(Wr + (size_t)d * NEXP);
        floatx4 w1 = *(const floatx4*)(Wr + (size_t)d * NEXP + 4);
#pragma unroll
        for (int e = 0; e < 4; e++) { acc[e] += xv * w0[e]; acc[e + 4] += xv * w1[e]; }
    }
#pragma unroll
    for (int e = 0; e < NEXP; e++) {
#pragma unroll
        for (int off = 32; off; off >>= 1) acc[e] += __shfl_xor(acc[e], off, 64);
    }
    if (l == 0) {
        float lg[NEXP];
#pragma unroll
        for (int e = 0; e < NEXP; e++) lg[e] = acc[e] + br[e];
        int e0 = 0;
#pragma unroll
        for (int e = 1; e < NEXP; e++) if (lg[e] > lg[e0]) e0 = e;
        int e1 = -1;
#pragma unroll
        for (int e = 0; e < NEXP; e++) {
            if (e == e0) continue;
            if (e1 < 0 || lg[e] > lg[e1]) e1 = e;
        }
        float w0 = 1.f / (1.f + expf(lg[e1] - lg[e0]));
        float w1 = 1.f - w0;
        int s0 = atomicAdd(&counts[e0], 1);
        tlist[e0 * T_TOK + s0] = t;
        wlist[e0 * T_TOK + s0] = w0;
        int s1 = atomicAdd(&counts[e1], 1);
        tlist[e1 * T_TOK + s1] = t | (1 << 16);
        wlist[e1 * T_TOK + s1] = w1;
    }
}

// ------------------------------------------------- grouped GEMM, m97 structure
// A: bf16 [rows][K] (gathered rows). Wt: bf16 [e][n][K] (pre-transposed).
// 128x128 tile, BK=32, 4 waves. Both operands staged via global_load_lds w=16
// into LDS layout [q=k/8][row][8] (byte = q*2048 + row*16): linear-writable
// (chunk c=i*4+wv covers q=c>>1, rows (c&1)*64..+64, lane l at +l*16) and
// 2-way-max bank conflict on ds_read_b128 (free).
// MODE 0: H[tok*2+rk] = gelu(Xb_g @ Wt1 + b1)   N=4096, K=1024
// MODE 1: out[tok]   += w*(H_g @ Wt2 + b2)      N=1024, K=4096 (2 kc chunks)
template <int MODE>
__global__ __launch_bounds__(256, 2) void moe_gemm2(
    const ushort* __restrict__ A, const ushort* __restrict__ Wt,
    const float* __restrict__ bias, const int* __restrict__ counts,
    const int* __restrict__ tlist, const float* __restrict__ wlist,
    ushort* __restrict__ Hout, float* __restrict__ Yout)
{
    constexpr int NTOT  = MODE ? DIM : HID;   // N
    constexpr int KFULL = MODE ? HID : DIM;   // full K = row length of A and Wt
    constexpr int KLEN  = MODE ? 2048 : 1024; // K handled by this block

    int bx = blockIdx.x;
    int e, mt, nt, kc;
    if (MODE == 0) { e = bx >> 9; mt = (bx >> 5) & 15; nt = bx & 31; kc = 0; }
    else { e = bx >> 8; int rr = bx & 255; mt = rr >> 4; nt = (rr >> 1) & 7; kc = rr & 1; }

    int Ne = counts[e];
    if (mt * 128 >= Ne) return;

    __shared__ ushort ldsA[4096];   // 8KB: [q][row][8]
    __shared__ ushort ldsB[4096];   // 8KB: [q][n][8]

    int tid = threadIdx.x, wv = tid >> 6, l = tid & 63;
    int srow = (wv & 1) * 64 + l;   // staging row within 128-tile
    int kq = (wv >> 1) * 8;         // staging k sub-offset (shorts); i=1 adds 16

    int slot = mt * 128 + srow; if (slot >= Ne) slot = Ne - 1;
    int packed = tlist[e * T_TOK + slot];
    int tok = packed & 0xFFFF, rk = (packed >> 16) & 1;
    size_t arow = MODE ? (size_t)(tok * 2 + rk) : (size_t)tok;
    const ushort* aptr = A + arow * KFULL + kc * 2048 + kq;
    const ushort* bptr = Wt + (size_t)e * NTOT * KFULL
                            + (size_t)(nt * 128 + srow) * KFULL + kc * 2048 + kq;

    ushort* la0 = &ldsA[wv * 512];           // chunk wv
    ushort* la1 = &ldsA[2048 + wv * 512];    // chunk 4+wv
    ushort* lb0 = &ldsB[wv * 512];
    ushort* lb1 = &ldsB[2048 + wv * 512];

    int wm = wv >> 1, wn = wv & 1, q = l >> 4, lr = l & 15;
    int aoff[4], boff[4];
#pragma unroll
    for (int mi = 0; mi < 4; mi++) aoff[mi] = q * 1024 + (wm * 64 + mi * 16 + lr) * 8;
#pragma unroll
    for (int ni = 0; ni < 4; ni++) boff[ni] = q * 1024 + (wn * 64 + ni * 16 + lr) * 8;

    floatx4 zz = {0.f, 0.f, 0.f, 0.f};
    floatx4 acc[4][4];
#pragma unroll
    for (int mi = 0; mi < 4; mi++)
#pragma unroll
        for (int ni = 0; ni < 4; ni++) acc[mi][ni] = zz;

    for (int k0 = 0; k0 < KLEN; k0 += 32) {
        __syncthreads();                 // prev iteration's ds_reads retired
        glds16(aptr + k0,      la0);     // async DMA: A 8KB + B 8KB
        glds16(aptr + k0 + 16, la1);
        glds16(bptr + k0,      lb0);
        glds16(bptr + k0 + 16, lb1);
        __syncthreads();                 // vmcnt(0) drain + staging visible

        short8 af[4], bfv[4];
#pragma unroll
        for (int mi = 0; mi < 4; mi++) af[mi] = *(const short8*)&ldsA[aoff[mi]];
#pragma unroll
        for (int ni = 0; ni < 4; ni++) bfv[ni] = *(const short8*)&ldsB[boff[ni]];
#pragma unroll
        for (int mi = 0; mi < 4; mi++)
#pragma unroll
            for (int ni = 0; ni < 4; ni++)
                acc[mi][ni] = __builtin_amdgcn_mfma_f32_16x16x32_bf16(
                    af[mi], bfv[ni], acc[mi][ni], 0, 0, 0);
    }

    // --- epilogue: C/D col=lane&15, row=quad*4+reg ---
#pragma unroll
    for (int mi = 0; mi < 4; mi++) {
        int rbase = wm * 64 + mi * 16 + q * 4;
#pragma unroll
        for (int j = 0; j < 4; j++) {
            int slot2 = mt * 128 + rbase + j;
            if (slot2 >= Ne) continue;   // pad rows: must skip (atomicAdd!)
            int pk2 = tlist[e * T_TOK + slot2];
            int tok2 = pk2 & 0xFFFF, rk2 = (pk2 >> 16) & 1;
#pragma unroll
            for (int ni = 0; ni < 4; ni++) {
                int col = nt * 128 + wn * 64 + ni * 16 + lr;
                float v = acc[mi][ni][j];
                float bc = bias[e * NTOT + col];
                if (MODE == 0) {
                    v = gelu_exact(v + bc);
                    Hout[(size_t)(tok2 * 2 + rk2) * HID + col] = f2bf(v);
                } else {
                    if (kc == 0) v += bc;
                    v *= wlist[e * T_TOK + slot2];
                    atomicAdd(&Yout[(size_t)tok2 * DIM + col], v);
                }
            }
        }
    }
}

// ================= fallback path (previous proven kernel, ws < 105 MB) =======
template <int MODE>
__global__ __launch_bounds__(256, 2) void moe_gemm(
    const ushort* __restrict__ A, const float* __restrict__ W,
    const float* __restrict__ bias, const int* __restrict__ counts,
    const int* __restrict__ tlist, const float* __restrict__ wlist,
    ushort* __restrict__ Hout, float* __restrict__ Yacc)
{
    constexpr int NTOT = MODE ? DIM : HID;
    constexpr int AROW = MODE ? HID : DIM;
    constexpr int KLEN = MODE ? 2048 : 1024;

    int bx = blockIdx.x;
    int e, mt, nt, kc;
    if (MODE == 0) { e = bx >> 9; mt = (bx >> 5) & 15; nt = bx & 31; kc = 0; }
    else { e = bx >> 8; int r = bx & 255; mt = r >> 4; nt = (r >> 1) & 7; kc = r & 1; }

    int Ne = counts[e];
    if (mt * 128 >= Ne) return;

    size_t wbase = (size_t)e * DIM * HID + (size_t)kc * 2048 * NTOT + (size_t)nt * 128;

    __shared__ ushort ldsA[128 * 40];
    __shared__ ushort ldsB[128 * 36];

    int tid = threadIdx.x;
    int wv = tid >> 6, l = tid & 63;

    const ushort* arowp[2]; int apos[2];
#pragma unroll
    for (int i = 0; i < 2; i++) {
        int idx = i * 256 + tid;
        int r = idx >> 2, p = idx & 3;
        int slot = mt * 128 + r; if (slot >= Ne) slot = Ne - 1;
        int packed = tlist[e * T_TOK + slot];
        int tok = packed & 0xFFFF, rk = (packed >> 16) & 1;
        size_t arow = MODE ? (size_t)(tok * 2 + rk) : (size_t)tok;
        arowp[i] = A + arow * AROW + (MODE ? kc * 2048 : 0) + p * 8;
        apos[i] = r * 40 + p * 8;
    }

    int kp = tid & 15;
    int n8 = tid >> 4;
    size_t boffg = wbase + (size_t)(2 * kp) * NTOT + n8 * 8;

    int wm = wv >> 1, wn = wv & 1;
    int q = l >> 4;
    int aoff[4], boff[4];
#pragma unroll
    for (int mi = 0; mi < 4; mi++)
        aoff[mi] = (wm * 64 + mi * 16 + (l & 15)) * 40 + q * 8;
#pragma unroll
    for (int ni = 0; ni < 4; ni++)
        boff[ni] = (wn * 64 + ni * 16 + (l & 15)) * 36 + q * 8;

    floatx4 zz = {0.f, 0.f, 0.f, 0.f};
    floatx4 acc[4][4];
#pragma unroll
    for (int mi = 0; mi < 4; mi++)
#pragma unroll
        for (int ni = 0; ni < 4; ni++) acc[mi][ni] = zz;

    for (int k0 = 0; k0 < KLEN; k0 += 32) {
        intx4 av[2];
#pragma unroll
        for (int i = 0; i < 2; i++) av[i] = *(const intx4*)(arowp[i] + k0);
        const float* p0 = W + boffg + (size_t)k0 * NTOT;
        const float* p1 = p0 + NTOT;
        floatx4 a0 = *(const floatx4*)(p0);
        floatx4 a1 = *(const floatx4*)(p0 + 4);
        floatx4 b0 = *(const floatx4*)(p1);
        floatx4 b1 = *(const floatx4*)(p1 + 4);
        uint32_t pr[8];
#pragma unroll
        for (int j = 0; j < 8; j++) {
            float va = (j < 4) ? a0[j & 3] : a1[j & 3];
            float vb = (j < 4) ? b0[j & 3] : b1[j & 3];
            pr[j] = (uint32_t)f2bf(va) | ((uint32_t)f2bf(vb) << 16);
        }

        __syncthreads();
#pragma unroll
        for (int i = 0; i < 2; i++) *(intx4*)&ldsA[apos[i]] = av[i];
#pragma unroll
        for (int j = 0; j < 8; j++)
            *(uint32_t*)&ldsB[(n8 * 8 + j) * 36 + 2 * kp] = pr[j];
        __syncthreads();

        short8 af[4], bf[4];
#pragma unroll
        for (int mi = 0; mi < 4; mi++) af[mi] = *(const short8*)&ldsA[aoff[mi]];
#pragma unroll
        for (int ni = 0; ni < 4; ni++) {
            short4v blo = *(const short4v*)&ldsB[boff[ni]];
            short4v bhi = *(const short4v*)&ldsB[boff[ni] + 4];
            bf[ni] = __builtin_shufflevector(blo, bhi, 0, 1, 2, 3, 4, 5, 6, 7);
        }
#pragma unroll
        for (int mi = 0; mi < 4; mi++)
#pragma unroll
            for (int ni = 0; ni < 4; ni++)
                acc[mi][ni] = __builtin_amdgcn_mfma_f32_16x16x32_bf16(
                    af[mi], bf[ni], acc[mi][ni], 0, 0, 0);
    }

#pragma unroll
    for (int mi = 0; mi < 4; mi++) {
        int rbase = wm * 64 + mi * 16 + q * 4;
#pragma unroll
        for (int j = 0; j < 4; j++) {
            int slot = mt * 128 + rbase + j;
            if (slot >= Ne) continue;
            int packed = tlist[e * T_TOK + slot];
            int tok = packed & 0xFFFF, rk = (packed >> 16) & 1;
#pragma unroll
            for (int ni = 0; ni < 4; ni++) {
                int col = nt * 128 + wn * 64 + ni * 16 + (l & 15);
                float v = acc[mi][ni][j];
                float bc = bias[e * NTOT + col];
                if (MODE == 0) {
                    v = gelu_exact(v + bc);
                    Hout[(size_t)(tok * 2 + rk) * HID + col] = f2bf(v);
                } else {
                    if (kc == 0) v += bc;
                    v *= wlist[e * T_TOK + slot];
                    atomicAdd(&Yacc[(size_t)tok * DIM + col], v);
                }
            }
        }
    }
}

__global__ __launch_bounds__(256) void combine_kernel(
    const float* __restrict__ Y, float* __restrict__ out)
{
    int i = (blockIdx.x * 256 + threadIdx.x) * 4;
    *(floatx4*)(out + i) = *(const floatx4*)(Y + i);
}

// ------------------------------------------------- launch
extern "C" void kernel_launch(void* const* d_in, const int* in_sizes, int n_in,
                              void* d_out, int out_size, void* d_ws, size_t ws_size,
                              hipStream_t stream) {
    const float* x  = (const float*)d_in[0];
    const float* Wr = (const float*)d_in[1];
    const float* br = (const float*)d_in[2];
    const float* W1 = (const float*)d_in[3];
    const float* b1 = (const float*)d_in[4];
    const float* W2 = (const float*)d_in[5];
    const float* b2 = (const float*)d_in[6];
    float* out = (float*)d_out;
    char* ws = (char*)d_ws;

    if (ws_size >= 104988928ULL) {
        // new path: bf16 pre-cast/transposed weights + m97-style GEMM.
        // layout: counts@0(256B) tlist@256(64K) wlist@65792(64K)
        //         Xb@131328(4MB) Hbuf@4325632(33.55MB) Wt@37880064(67.1MB)
        // Wt holds Wt1 for gemm<0>, then is overwritten with Wt2 for gemm<1>.
        int*    counts = (int*)ws;
        int*    tlist  = (int*)(ws + 256);
        float*  wlist  = (float*)(ws + 65792);
        ushort* Xb     = (ushort*)(ws + 131328);
        ushort* Hbuf   = (ushort*)(ws + 4325632);
        ushort* Wt     = (ushort*)(ws + 37880064);

        hipMemsetAsync(counts, 0, 256, stream);
        hipMemsetAsync(out, 0, (size_t)T_TOK * DIM * sizeof(float), stream);
        cast_x_kernel<<<T_TOK * DIM / 2048, 256, 0, stream>>>(x, Xb);
        router_kernel<<<T_TOK / 4, 256, 0, stream>>>(x, Wr, br, counts, tlist, wlist);
        transpose_cast_kernel<<<dim3(HID / 64, DIM / 64, NEXP), 256, 0, stream>>>(
            W1, Wt, DIM, HID);
        moe_gemm2<0><<<NEXP * 16 * 32, 256, 0, stream>>>(
            Xb, Wt, b1, counts, tlist, wlist, Hbuf, nullptr);
        transpose_cast_kernel<<<dim3(DIM / 64, HID / 64, NEXP), 256, 0, stream>>>(
            W2, Wt, HID, DIM);
        moe_gemm2<1><<<NEXP * 16 * 8 * 2, 256, 0, stream>>>(
            Hbuf, Wt, b2, counts, tlist, wlist, nullptr, out);
    } else {
        // fallback: previous proven path (42.07 MB)
        int*    counts = (int*)ws;
        int*    tlist  = (int*)(ws + 256);
        float*  wlist  = (float*)(ws + 256 + 65536);
        ushort* Hbuf   = (ushort*)(ws + 256 + 131072);
        float*  Yacc   = (float*)(ws + 256 + 131072 + 33554432);
        ushort* Xb     = (ushort*)Yacc;

        hipMemsetAsync(counts, 0, 256, stream);
        cast_x_kernel<<<T_TOK * DIM / 2048, 256, 0, stream>>>(x, Xb);
        router_kernel<<<T_TOK / 4, 256, 0, stream>>>(x, Wr, br, counts, tlist, wlist);
        moe_gemm<0><<<NEXP * 16 * 32, 256, 0, stream>>>(Xb, W1, b1, counts, tlist, wlist, Hbuf, nullptr);
        hipMemsetAsync(Yacc, 0, (size_t)T_TOK * DIM * sizeof(float), stream);
        moe_gemm<1><<<NEXP * 16 * 8 * 2, 256, 0, stream>>>(Hbuf, W2, b2, counts, tlist, wlist, nullptr, Yacc);
        combine_kernel<<<out_size / 1024, 256, 0, stream>>>(Yacc, out);
    }
}

// Round 2
// 607.085 us; speedup vs baseline: 1.0821x; 1.0821x over previous
//
#include <hip/hip_runtime.h>
#include <stdint.h>

#define T_TOK 2048
#define DIM   1024
#define HID   4096
#define NEXP  8

typedef __attribute__((ext_vector_type(8))) short  short8;
typedef __attribute__((ext_vector_type(4))) short  short4v;
typedef __attribute__((ext_vector_type(4))) float  floatx4;
typedef __attribute__((ext_vector_type(4))) int    intx4;

__device__ __forceinline__ ushort f2bf(float f) {
    union { float f; uint32_t i; } v; v.f = f;
    uint32_t r = v.i + 0x7FFFu + ((v.i >> 16) & 1u);
    return (ushort)(r >> 16);
}
__device__ __forceinline__ float gelu_exact(float x) {
    return 0.5f * x * (1.0f + erff(x * 0.70710678118654752f));
}
// async global->LDS DMA, 16B/lane; LDS base wave-uniform, global src per-lane.
__device__ __forceinline__ void glds16(const ushort* g, ushort* lds) {
    __builtin_amdgcn_global_load_lds(
        (const __attribute__((address_space(1))) unsigned int*)g,
        (__attribute__((address_space(3))) unsigned int*)lds, 16, 0, 0);
}

// ------------------------------------------------- x (fp32) -> bf16 Xb
__global__ __launch_bounds__(256) void cast_x_kernel(
    const float* __restrict__ x, ushort* __restrict__ Xb)
{
    int i = (blockIdx.x * 256 + threadIdx.x) * 8;
    floatx4 a = *(const floatx4*)(x + i);
    floatx4 b = *(const floatx4*)(x + i + 4);
    uint32_t o[4];
    o[0] = (uint32_t)f2bf(a[0]) | ((uint32_t)f2bf(a[1]) << 16);
    o[1] = (uint32_t)f2bf(a[2]) | ((uint32_t)f2bf(a[3]) << 16);
    o[2] = (uint32_t)f2bf(b[0]) | ((uint32_t)f2bf(b[1]) << 16);
    o[3] = (uint32_t)f2bf(b[2]) | ((uint32_t)f2bf(b[3]) << 16);
    *(intx4*)(Xb + i) = *(const intx4*)o;
}

// ------------------------------------------------- W (fp32 [R][C]) -> bf16 [C][R]
__global__ __launch_bounds__(256) void transpose_cast_kernel(
    const float* __restrict__ in, ushort* __restrict__ out, int R, int C)
{
    __shared__ float tile[64][65];
    int e = blockIdx.z;
    int rb = blockIdx.y * 64, cb = blockIdx.x * 64;
    const float* ip = in + (size_t)e * R * C;
    ushort* op = out + (size_t)e * R * C;
    int t = threadIdx.x;
    int tr = t >> 4, tc4 = (t & 15) * 4;
#pragma unroll
    for (int i = 0; i < 4; i++) {
        int r = i * 16 + tr;
        floatx4 v = *(const floatx4*)(ip + (size_t)(rb + r) * C + cb + tc4);
        tile[r][tc4] = v[0]; tile[r][tc4 + 1] = v[1];
        tile[r][tc4 + 2] = v[2]; tile[r][tc4 + 3] = v[3];
    }
    __syncthreads();
    int cc = t >> 2, rseg = (t & 3) * 16;
#pragma unroll
    for (int s = 0; s < 2; s++) {
        ushort o[8];
#pragma unroll
        for (int j = 0; j < 8; j++) o[j] = f2bf(tile[rseg + s * 8 + j][cc]);
        *(intx4*)(op + (size_t)(cb + cc) * R + rb + rseg + s * 8) = *(const intx4*)o;
    }
}

// ------------------------------------------------- router (fp32)
__global__ __launch_bounds__(256) void router_kernel(
    const float* __restrict__ x, const float* __restrict__ Wr,
    const float* __restrict__ br, int* __restrict__ counts,
    int* __restrict__ tlist, float* __restrict__ wlist)
{
    int wv = threadIdx.x >> 6, l = threadIdx.x & 63;
    int t = blockIdx.x * 4 + wv;
    float acc[NEXP];
#pragma unroll
    for (int e = 0; e < NEXP; e++) acc[e] = 0.f;
    const float* xr = x + (size_t)t * DIM;
    for (int d = l; d < DIM; d += 64) {
        float xv = xr[d];
        floatx4 w0 = *(const floatx4*)(Wr + (size_t)d * NEXP);
        floatx4 w1 = *(const floatx4*)(Wr + (size_t)d * NEXP + 4);
#pragma unroll
        for (int e = 0; e < 4; e++) { acc[e] += xv * w0[e]; acc[e + 4] += xv * w1[e]; }
    }
#pragma unroll
    for (int e = 0; e < NEXP; e++) {
#pragma unroll
        for (int off = 32; off; off >>= 1) acc[e] += __shfl_xor(acc[e], off, 64);
    }
    if (l == 0) {
        float lg[NEXP];
#pragma unroll
        for (int e = 0; e < NEXP; e++) lg[e] = acc[e] + br[e];
        int e0 = 0;
#pragma unroll
        for (int e = 1; e < NEXP; e++) if (lg[e] > lg[e0]) e0 = e;
        int e1 = -1;
#pragma unroll
        for (int e = 0; e < NEXP; e++) {
            if (e == e0) continue;
            if (e1 < 0 || lg[e] > lg[e1]) e1 = e;
        }
        float w0 = 1.f / (1.f + expf(lg[e1] - lg[e0]));
        float w1 = 1.f - w0;
        int s0 = atomicAdd(&counts[e0], 1);
        tlist[e0 * T_TOK + s0] = t;
        wlist[e0 * T_TOK + s0] = w0;
        int s1 = atomicAdd(&counts[e1], 1);
        tlist[e1 * T_TOK + s1] = t | (1 << 16);
        wlist[e1 * T_TOK + s1] = w1;
    }
}

// ------------------------------------------------- grouped GEMM, 2-phase pipeline
// 128x128 tile, BK=64, 4 waves, double-buffered LDS (64KB), counted vmcnt.
// LDS layout per buf/operand: [q=k/8][row][8 shorts] (byte=q*2048+row*16):
// linearly writable by glds16 AND conflict-free on ds_read_b128 (measured 0).
// Pipeline per K-tile t: BAR(all waves done reading buf^1) -> STAGE(t+1->buf^1,
// 8 glds) -> s_waitcnt vmcnt(8) (tile-t loads done, t+1's stay IN FLIGHT) ->
// BAR -> 32 MFMA/wave on buf. T3/T4 recipe (m218/m248: counted vmcnt is the gain).
template <int MODE>
__global__ __launch_bounds__(256, 2) void moe_gemm3(
    const ushort* __restrict__ A, const ushort* __restrict__ Wt,
    const float* __restrict__ bias, const int* __restrict__ counts,
    const int* __restrict__ tlist, const float* __restrict__ wlist,
    ushort* __restrict__ Hout, float* __restrict__ Yout)
{
    constexpr int NTOT  = MODE ? DIM : HID;   // N
    constexpr int KFULL = MODE ? HID : DIM;   // row length of A and Wt
    constexpr int KLEN  = MODE ? 2048 : 1024; // K handled by this block
    constexpr int NTILE = KLEN / 64;          // K-tiles of BK=64

    int bx = blockIdx.x;
    int e, mt, nt, kc;
    if (MODE == 0) { e = bx >> 9; mt = (bx >> 5) & 15; nt = bx & 31; kc = 0; }
    else { e = bx >> 8; int rr = bx & 255; mt = rr >> 4; nt = (rr >> 1) & 7; kc = rr & 1; }

    int Ne = counts[e];
    if (mt * 128 >= Ne) return;

    __shared__ ushort lds[32768];   // 64KB: [buf:16384][op:8192][q:1024][row*8]

    int tid = threadIdx.x, wv = tid >> 6, l = tid & 63;

    // --- staging sources: 2 gathered A rows + 2 B rows per thread ---
    int s0 = mt * 128 + l;      if (s0 >= Ne) s0 = Ne - 1;
    int s1 = mt * 128 + 64 + l; if (s1 >= Ne) s1 = Ne - 1;
    int p0 = tlist[e * T_TOK + s0], p1 = tlist[e * T_TOK + s1];
    size_t ar0 = MODE ? (size_t)((p0 & 0xFFFF) * 2 + ((p0 >> 16) & 1)) : (size_t)(p0 & 0xFFFF);
    size_t ar1 = MODE ? (size_t)((p1 & 0xFFFF) * 2 + ((p1 >> 16) & 1)) : (size_t)(p1 & 0xFFFF);
    const ushort* asrc0 = A + ar0 * KFULL + kc * 2048;
    const ushort* asrc1 = A + ar1 * KFULL + kc * 2048;
    const ushort* bsrc0 = Wt + (size_t)e * NTOT * KFULL
                             + (size_t)(nt * 128 + l) * KFULL + kc * 2048;
    const ushort* bsrc1 = bsrc0 + (size_t)64 * KFULL;
    int q0 = wv, q1 = wv + 4;   // the two k-chunks (of 8 shorts) this wave stages

#define STAGE(buf, t) do {                                             \
        ushort* Lb = &lds[(buf) * 16384];                              \
        int ko = (t) * 64;                                             \
        glds16(asrc0 + ko + q0 * 8, Lb + q0 * 1024);                   \
        glds16(asrc0 + ko + q1 * 8, Lb + q1 * 1024);                   \
        glds16(asrc1 + ko + q0 * 8, Lb + q0 * 1024 + 512);             \
        glds16(asrc1 + ko + q1 * 8, Lb + q1 * 1024 + 512);             \
        glds16(bsrc0 + ko + q0 * 8, Lb + 8192 + q0 * 1024);            \
        glds16(bsrc0 + ko + q1 * 8, Lb + 8192 + q1 * 1024);            \
        glds16(bsrc1 + ko + q0 * 8, Lb + 8192 + q0 * 1024 + 512);      \
        glds16(bsrc1 + ko + q1 * 8, Lb + 8192 + q1 * 1024 + 512);      \
    } while (0)

    // --- fragment read offsets (shorts) ---
    int wm = wv >> 1, wn = wv & 1, q4 = l >> 4, lr = l & 15;
    int aro[4], bro[4];
#pragma unroll
    for (int mi = 0; mi < 4; mi++) aro[mi] = (wm * 64 + mi * 16 + lr) * 8;
#pragma unroll
    for (int ni = 0; ni < 4; ni++) bro[ni] = 8192 + (wn * 64 + ni * 16 + lr) * 8;

    floatx4 zz = {0.f, 0.f, 0.f, 0.f};
    floatx4 acc[4][4];
#pragma unroll
    for (int mi = 0; mi < 4; mi++)
#pragma unroll
        for (int ni = 0; ni < 4; ni++) acc[mi][ni] = zz;

    STAGE(0, 0);                       // prologue: tile 0 in flight (8 loads)
    int cur = 0;
    for (int t = 0; t < NTILE; ++t) {
        asm volatile("" ::: "memory");
        __builtin_amdgcn_s_barrier();  // all waves done reading buf cur^1
        asm volatile("" ::: "memory");
        if (t + 1 < NTILE) {
            STAGE(cur ^ 1, t + 1);     // issue next tile (stays in flight)
            asm volatile("s_waitcnt vmcnt(8)" ::: "memory");  // tile t landed
        } else {
            asm volatile("s_waitcnt vmcnt(0)" ::: "memory");
        }
        __builtin_amdgcn_s_barrier();  // tile t visible to all waves
        asm volatile("" ::: "memory");

        const ushort* Lp = &lds[cur * 16384];
        short8 af[4], bfv[4];
#pragma unroll
        for (int kk = 0; kk < 2; ++kk) {
            int qb = (kk * 4 + q4) * 1024;
#pragma unroll
            for (int ni = 0; ni < 4; ni++) bfv[ni] = *(const short8*)&Lp[qb + bro[ni]];
#pragma unroll
            for (int mi = 0; mi < 4; mi++) af[mi] = *(const short8*)&Lp[qb + aro[mi]];
#pragma unroll
            for (int mi = 0; mi < 4; mi++)
#pragma unroll
                for (int ni = 0; ni < 4; ni++)
                    acc[mi][ni] = __builtin_amdgcn_mfma_f32_16x16x32_bf16(
                        af[mi], bfv[ni], acc[mi][ni], 0, 0, 0);
        }
        cur ^= 1;
    }
#undef STAGE

    // --- epilogue: C/D col=lane&15, row=quad*4+reg ---
#pragma unroll
    for (int mi = 0; mi < 4; mi++) {
        int rbase = wm * 64 + mi * 16 + q4 * 4;
#pragma unroll
        for (int j = 0; j < 4; j++) {
            int slot2 = mt * 128 + rbase + j;
            if (slot2 >= Ne) continue;   // pad rows: must skip (atomicAdd!)
            int pk2 = tlist[e * T_TOK + slot2];
            int tok2 = pk2 & 0xFFFF, rk2 = (pk2 >> 16) & 1;
#pragma unroll
            for (int ni = 0; ni < 4; ni++) {
                int col = nt * 128 + wn * 64 + ni * 16 + lr;
                float v = acc[mi][ni][j];
                float bc = bias[e * NTOT + col];
                if (MODE == 0) {
                    v = gelu_exact(v + bc);
                    Hout[(size_t)(tok2 * 2 + rk2) * HID + col] = f2bf(v);
                } else {
                    if (kc == 0) v += bc;
                    v *= wlist[e * T_TOK + slot2];
                    atomicAdd(&Yout[(size_t)tok2 * DIM + col], v);
                }
            }
        }
    }
}

// ================= fallback path (proven kernel, ws < 105 MB) ================
template <int MODE>
__global__ __launch_bounds__(256, 2) void moe_gemm(
    const ushort* __restrict__ A, const float* __restrict__ W,
    const float* __restrict__ bias, const int* __restrict__ counts,
    const int* __restrict__ tlist, const float* __restrict__ wlist,
    ushort* __restrict__ Hout, float* __restrict__ Yacc)
{
    constexpr int NTOT = MODE ? DIM : HID;
    constexpr int AROW = MODE ? HID : DIM;
    constexpr int KLEN = MODE ? 2048 : 1024;

    int bx = blockIdx.x;
    int e, mt, nt, kc;
    if (MODE == 0) { e = bx >> 9; mt = (bx >> 5) & 15; nt = bx & 31; kc = 0; }
    else { e = bx >> 8; int r = bx & 255; mt = r >> 4; nt = (r >> 1) & 7; kc = r & 1; }

    int Ne = counts[e];
    if (mt * 128 >= Ne) return;

    size_t wbase = (size_t)e * DIM * HID + (size_t)kc * 2048 * NTOT + (size_t)nt * 128;

    __shared__ ushort ldsA[128 * 40];
    __shared__ ushort ldsB[128 * 36];

    int tid = threadIdx.x;
    int wv = tid >> 6, l = tid & 63;

    const ushort* arowp[2]; int apos[2];
#pragma unroll
    for (int i = 0; i < 2; i++) {
        int idx = i * 256 + tid;
        int r = idx >> 2, p = idx & 3;
        int slot = mt * 128 + r; if (slot >= Ne) slot = Ne - 1;
        int packed = tlist[e * T_TOK + slot];
        int tok = packed & 0xFFFF, rk = (packed >> 16) & 1;
        size_t arow = MODE ? (size_t)(tok * 2 + rk) : (size_t)tok;
        arowp[i] = A + arow * AROW + (MODE ? kc * 2048 : 0) + p * 8;
        apos[i] = r * 40 + p * 8;
    }

    int kp = tid & 15;
    int n8 = tid >> 4;
    size_t boffg = wbase + (size_t)(2 * kp) * NTOT + n8 * 8;

    int wm = wv >> 1, wn = wv & 1;
    int q = l >> 4;
    int aoff[4], boff[4];
#pragma unroll
    for (int mi = 0; mi < 4; mi++)
        aoff[mi] = (wm * 64 + mi * 16 + (l & 15)) * 40 + q * 8;
#pragma unroll
    for (int ni = 0; ni < 4; ni++)
        boff[ni] = (wn * 64 + ni * 16 + (l & 15)) * 36 + q * 8;

    floatx4 zz = {0.f, 0.f, 0.f, 0.f};
    floatx4 acc[4][4];
#pragma unroll
    for (int mi = 0; mi < 4; mi++)
#pragma unroll
        for (int ni = 0; ni < 4; ni++) acc[mi][ni] = zz;

    for (int k0 = 0; k0 < KLEN; k0 += 32) {
        intx4 av[2];
#pragma unroll
        for (int i = 0; i < 2; i++) av[i] = *(const intx4*)(arowp[i] + k0);
        const float* p0 = W + boffg + (size_t)k0 * NTOT;
        const float* p1 = p0 + NTOT;
        floatx4 a0 = *(const floatx4*)(p0);
        floatx4 a1 = *(const floatx4*)(p0 + 4);
        floatx4 b0 = *(const floatx4*)(p1);
        floatx4 b1 = *(const floatx4*)(p1 + 4);
        uint32_t pr[8];
#pragma unroll
        for (int j = 0; j < 8; j++) {
            float va = (j < 4) ? a0[j & 3] : a1[j & 3];
            float vb = (j < 4) ? b0[j & 3] : b1[j & 3];
            pr[j] = (uint32_t)f2bf(va) | ((uint32_t)f2bf(vb) << 16);
        }

        __syncthreads();
#pragma unroll
        for (int i = 0; i < 2; i++) *(intx4*)&ldsA[apos[i]] = av[i];
#pragma unroll
        for (int j = 0; j < 8; j++)
            *(uint32_t*)&ldsB[(n8 * 8 + j) * 36 + 2 * kp] = pr[j];
        __syncthreads();

        short8 af[4], bf[4];
#pragma unroll
        for (int mi = 0; mi < 4; mi++) af[mi] = *(const short8*)&ldsA[aoff[mi]];
#pragma unroll
        for (int ni = 0; ni < 4; ni++) {
            short4v blo = *(const short4v*)&ldsB[boff[ni]];
            short4v bhi = *(const short4v*)&ldsB[boff[ni] + 4];
            bf[ni] = __builtin_shufflevector(blo, bhi, 0, 1, 2, 3, 4, 5, 6, 7);
        }
#pragma unroll
        for (int mi = 0; mi < 4; mi++)
#pragma unroll
            for (int ni = 0; ni < 4; ni++)
                acc[mi][ni] = __builtin_amdgcn_mfma_f32_16x16x32_bf16(
                    af[mi], bf[ni], acc[mi][ni], 0, 0, 0);
    }

#pragma unroll
    for (int mi = 0; mi < 4; mi++) {
        int rbase = wm * 64 + mi * 16 + q * 4;
#pragma unroll
        for (int j = 0; j < 4; j++) {
            int slot = mt * 128 + rbase + j;
            if (slot >= Ne) continue;
            int packed = tlist[e * T_TOK + slot];
            int tok = packed & 0xFFFF, rk = (packed >> 16) & 1;
#pragma unroll
            for (int ni = 0; ni < 4; ni++) {
                int col = nt * 128 + wn * 64 + ni * 16 + (l & 15);
                float v = acc[mi][ni][j];
                float bc = bias[e * NTOT + col];
                if (MODE == 0) {
                    v = gelu_exact(v + bc);
                    Hout[(size_t)(tok * 2 + rk) * HID + col] = f2bf(v);
                } else {
                    if (kc == 0) v += bc;
                    v *= wlist[e * T_TOK + slot];
                    atomicAdd(&Yacc[(size_t)tok * DIM + col], v);
                }
            }
        }
    }
}

__global__ __launch_bounds__(256) void combine_kernel(
    const float* __restrict__ Y, float* __restrict__ out)
{
    int i = (blockIdx.x * 256 + threadIdx.x) * 4;
    *(floatx4*)(out + i) = *(const floatx4*)(Y + i);
}

// ------------------------------------------------- launch
extern "C" void kernel_launch(void* const* d_in, const int* in_sizes, int n_in,
                              void* d_out, int out_size, void* d_ws, size_t ws_size,
                              hipStream_t stream) {
    const float* x  = (const float*)d_in[0];
    const float* Wr = (const float*)d_in[1];
    const float* br = (const float*)d_in[2];
    const float* W1 = (const float*)d_in[3];
    const float* b1 = (const float*)d_in[4];
    const float* W2 = (const float*)d_in[5];
    const float* b2 = (const float*)d_in[6];
    float* out = (float*)d_out;
    char* ws = (char*)d_ws;

    if (ws_size >= 104988928ULL) {
        // layout: counts@0(256B) tlist@256(64K) wlist@65792(64K)
        //         Xb@131328(4MB) Hbuf@4325632(33.55MB) Wt@37880064(67.1MB)
        int*    counts = (int*)ws;
        int*    tlist  = (int*)(ws + 256);
        float*  wlist  = (float*)(ws + 65792);
        ushort* Xb     = (ushort*)(ws + 131328);
        ushort* Hbuf   = (ushort*)(ws + 4325632);
        ushort* Wt     = (ushort*)(ws + 37880064);

        hipMemsetAsync(counts, 0, 256, stream);
        hipMemsetAsync(out, 0, (size_t)T_TOK * DIM * sizeof(float), stream);
        cast_x_kernel<<<T_TOK * DIM / 2048, 256, 0, stream>>>(x, Xb);
        router_kernel<<<T_TOK / 4, 256, 0, stream>>>(x, Wr, br, counts, tlist, wlist);
        transpose_cast_kernel<<<dim3(HID / 64, DIM / 64, NEXP), 256, 0, stream>>>(
            W1, Wt, DIM, HID);
        moe_gemm3<0><<<NEXP * 16 * 32, 256, 0, stream>>>(
            Xb, Wt, b1, counts, tlist, wlist, Hbuf, nullptr);
        transpose_cast_kernel<<<dim3(DIM / 64, HID / 64, NEXP), 256, 0, stream>>>(
            W2, Wt, HID, DIM);
        moe_gemm3<1><<<NEXP * 16 * 8 * 2, 256, 0, stream>>>(
            Hbuf, Wt, b2, counts, tlist, wlist, nullptr, out);
    } else {
        // fallback: previous proven path (42.07 MB)
        int*    counts = (int*)ws;
        int*    tlist  = (int*)(ws + 256);
        float*  wlist  = (float*)(ws + 256 + 65536);
        ushort* Hbuf   = (ushort*)(ws + 256 + 131072);
        float*  Yacc   = (float*)(ws + 256 + 131072 + 33554432);
        ushort* Xb     = (ushort*)Yacc;

        hipMemsetAsync(counts, 0, 256, stream);
        cast_x_kernel<<<T_TOK * DIM / 2048, 256, 0, stream>>>(x, Xb);
        router_kernel<<<T_TOK / 4, 256, 0, stream>>>(x, Wr, br, counts, tlist, wlist);
        moe_gemm<0><<<NEXP * 16 * 32, 256, 0, stream>>>(Xb, W1, b1, counts, tlist, wlist, Hbuf, nullptr);
        hipMemsetAsync(Yacc, 0, (size_t)T_TOK * DIM * sizeof(float), stream);
        moe_gemm<1><<<NEXP * 16 * 8 * 2, 256, 0, stream>>>(Hbuf, W2, b2, counts, tlist, wlist, nullptr, Yacc);
        combine_kernel<<<out_size / 1024, 256, 0, stream>>>(Yacc, out);
    }
}

// Round 3
// 536.845 us; speedup vs baseline: 1.2237x; 1.1308x over previous
//
#include <hip/hip_runtime.h>
#include <stdint.h>

#define T_TOK 2048
#define DIM   1024
#define HID   4096
#define NEXP  8

typedef __attribute__((ext_vector_type(8))) short  short8;
typedef __attribute__((ext_vector_type(4))) short  short4v;
typedef __attribute__((ext_vector_type(4))) float  floatx4;
typedef __attribute__((ext_vector_type(4))) int    intx4;

__device__ __forceinline__ ushort f2bf(float f) {
    union { float f; uint32_t i; } v; v.f = f;
    uint32_t r = v.i + 0x7FFFu + ((v.i >> 16) & 1u);
    return (ushort)(r >> 16);
}
__device__ __forceinline__ float gelu_exact(float x) {
    return 0.5f * x * (1.0f + erff(x * 0.70710678118654752f));
}
// async global->LDS DMA, 16B/lane; LDS base wave-uniform, global src per-lane.
__device__ __forceinline__ void glds16(const ushort* g, ushort* lds) {
    __builtin_amdgcn_global_load_lds(
        (const __attribute__((address_space(1))) unsigned int*)g,
        (__attribute__((address_space(3))) unsigned int*)lds, 16, 0, 0);
}

// ------------------------------------------------- x (fp32) -> bf16 Xb
__global__ __launch_bounds__(256) void cast_x_kernel(
    const float* __restrict__ x, ushort* __restrict__ Xb)
{
    int i = (blockIdx.x * 256 + threadIdx.x) * 8;
    floatx4 a = *(const floatx4*)(x + i);
    floatx4 b = *(const floatx4*)(x + i + 4);
    uint32_t o[4];
    o[0] = (uint32_t)f2bf(a[0]) | ((uint32_t)f2bf(a[1]) << 16);
    o[1] = (uint32_t)f2bf(a[2]) | ((uint32_t)f2bf(a[3]) << 16);
    o[2] = (uint32_t)f2bf(b[0]) | ((uint32_t)f2bf(b[1]) << 16);
    o[3] = (uint32_t)f2bf(b[2]) | ((uint32_t)f2bf(b[3]) << 16);
    *(intx4*)(Xb + i) = *(const intx4*)o;
}

// ------------------------------------------------- W (fp32 [R][C]) -> bf16 tiles
// out = [e][nb=C/128][kt=R/64] tiles of 8192 shorts, tile[r][s][8] where the
// slot s holds k-chunk c = s ^ (r&7)  (T2 swizzle baked in at write time).
// value = in[e][kt*64 + c*8 + j][nb*128 + r].
__global__ __launch_bounds__(256) void transpose_cast_tiled(
    const float* __restrict__ in, ushort* __restrict__ out, int R, int C)
{
    __shared__ float tl[64 * 132];
    int e = blockIdx.z, nb = blockIdx.y, kt = blockIdx.x;
    int NKT = R >> 6, NBLK = C >> 7;
    const float* ip = in + (size_t)e * R * C + (size_t)(kt * 64) * C + nb * 128;
    ushort* op = out + ((size_t)(e * NBLK + nb) * NKT + kt) * 8192;
    int t = threadIdx.x;
    int rr = t >> 2, cs = (t & 3) * 32;
#pragma unroll
    for (int j = 0; j < 8; j++) {
        floatx4 v = *(const floatx4*)(ip + (size_t)rr * C + cs + j * 4);
        *(floatx4*)&tl[rr * 132 + cs + j * 4] = v;
    }
    __syncthreads();
    int r = t >> 1, sb = (t & 1) * 4;
#pragma unroll
    for (int s2 = 0; s2 < 4; s2++) {
        int s = sb + s2;
        int c = s ^ (r & 7);
        ushort o[8];
#pragma unroll
        for (int j = 0; j < 8; j++) o[j] = f2bf(tl[(c * 8 + j) * 132 + r]);
        *(intx4*)(op + r * 64 + s * 8) = *(const intx4*)o;
    }
}

// ------------------------------------------------- router (fp32)
__global__ __launch_bounds__(256) void router_kernel(
    const float* __restrict__ x, const float* __restrict__ Wr,
    const float* __restrict__ br, int* __restrict__ counts,
    int* __restrict__ tlist, float* __restrict__ wlist)
{
    int wv = threadIdx.x >> 6, l = threadIdx.x & 63;
    int t = blockIdx.x * 4 + wv;
    float acc[NEXP];
#pragma unroll
    for (int e = 0; e < NEXP; e++) acc[e] = 0.f;
    const float* xr = x + (size_t)t * DIM;
    for (int d = l; d < DIM; d += 64) {
        float xv = xr[d];
        floatx4 w0 = *(const floatx4*)(Wr + (size_t)d * NEXP);
        floatx4 w1 = *(const floatx4*)(Wr + (size_t)d * NEXP + 4);
#pragma unroll
        for (int e = 0; e < 4; e++) { acc[e] += xv * w0[e]; acc[e + 4] += xv * w1[e]; }
    }
#pragma unroll
    for (int e = 0; e < NEXP; e++) {
#pragma unroll
        for (int off = 32; off; off >>= 1) acc[e] += __shfl_xor(acc[e], off, 64);
    }
    if (l == 0) {
        float lg[NEXP];
#pragma unroll
        for (int e = 0; e < NEXP; e++) lg[e] = acc[e] + br[e];
        int e0 = 0;
#pragma unroll
        for (int e = 1; e < NEXP; e++) if (lg[e] > lg[e0]) e0 = e;
        int e1 = -1;
#pragma unroll
        for (int e = 0; e < NEXP; e++) {
            if (e == e0) continue;
            if (e1 < 0 || lg[e] > lg[e1]) e1 = e;
        }
        float w0 = 1.f / (1.f + expf(lg[e1] - lg[e0]));
        float w1 = 1.f - w0;
        int s0 = atomicAdd(&counts[e0], 1);
        tlist[e0 * T_TOK + s0] = t;
        wlist[e0 * T_TOK + s0] = w0;
        int s1 = atomicAdd(&counts[e1], 1);
        tlist[e1 * T_TOK + s1] = t | (1 << 16);
        wlist[e1 * T_TOK + s1] = w1;
    }
}

// ------------------------------------------------- grouped GEMM, coalesced 2-phase
// 128x128 tile, BK=64, 4 waves, double-buffered LDS (64KB), counted vmcnt.
// LDS per buf: A[128r][64k] then B[128r][64k], rows 128B, slot s = chunk^(r&7)
// swizzle (2-way bank alias on ds_read_b128 = free). Staging:
//   B: pre-swizzled contiguous 16KB tiles -> glds16 source fully linear (1KB/inst)
//   A: lane l -> row (l>>3), chunk (l&7)^(l>>3): 128B runs per row (coalesced).
// Pipeline per K-tile t: BAR -> STAGE(t+1) -> vmcnt(8) (t landed, t+1 in flight)
// -> BAR -> 32 MFMA/wave.
template <int MODE>
__global__ __launch_bounds__(256, 2) void moe_gemm4(
    const ushort* __restrict__ A, const ushort* __restrict__ Wt,
    const float* __restrict__ bias, const int* __restrict__ counts,
    const int* __restrict__ tlist, const float* __restrict__ wlist,
    ushort* __restrict__ Hout, float* __restrict__ Yout)
{
    constexpr int NTOT  = MODE ? DIM : HID;   // N
    constexpr int KFULL = MODE ? HID : DIM;   // row length of A / full K
    constexpr int KLEN  = MODE ? 2048 : 1024; // K handled by this block
    constexpr int NTILE = KLEN / 64;
    constexpr int NBLK  = NTOT / 128;
    constexpr int NKT   = KFULL / 64;

    int bx = blockIdx.x;
    int e, mt, nt, kc;
    if (MODE == 0) { e = bx >> 9; mt = (bx >> 5) & 15; nt = bx & 31; kc = 0; }
    else { e = bx >> 8; int rr = bx & 255; mt = rr >> 4; nt = (rr >> 1) & 7; kc = rr & 1; }

    int Ne = counts[e];
    if (mt * 128 >= Ne) return;

    __shared__ ushort lds[32768];   // 64KB: [buf:16384][A:8192][B:8192] shorts

    int tid = threadIdx.x, wv = tid >> 6, l = tid & 63;
    int lr8 = l >> 3, lc8 = l & 7;
    int swz8 = (lc8 ^ lr8) * 8;     // A per-lane swizzled chunk offset (shorts)

    // --- A row pointers: 4 gathered rows per thread (rows wv*32+i*8+lr8) ---
    const ushort* aps[4];
#pragma unroll
    for (int i = 0; i < 4; i++) {
        int r = wv * 32 + i * 8 + lr8;
        int slot = mt * 128 + r; if (slot >= Ne) slot = Ne - 1;
        int pk = tlist[e * T_TOK + slot];
        size_t arow = MODE ? (size_t)((pk & 0xFFFF) * 2 + ((pk >> 16) & 1))
                           : (size_t)(pk & 0xFFFF);
        aps[i] = A + arow * KFULL + kc * 2048 + swz8;
    }
    // --- B: contiguous pre-swizzled tiles ---
    const ushort* bp = Wt + ((size_t)(e * NBLK + nt) * NKT + kc * 32) * 8192
                          + wv * 2048 + l * 8;

#define STAGE(buf, t) do {                                             \
        ushort* La = &lds[(buf) * 16384 + wv * 2048];                  \
        int ko = (t) * 64;                                             \
        glds16(aps[0] + ko, La);                                       \
        glds16(aps[1] + ko, La + 512);                                 \
        glds16(aps[2] + ko, La + 1024);                                \
        glds16(aps[3] + ko, La + 1536);                                \
        const ushort* bt = bp + (size_t)(t) * 8192;                    \
        ushort* Lb = La + 8192;                                        \
        glds16(bt,        Lb);                                         \
        glds16(bt + 512,  Lb + 512);                                   \
        glds16(bt + 1024, Lb + 1024);                                  \
        glds16(bt + 1536, Lb + 1536);                                  \
    } while (0)

    // --- fragment read offsets (shorts); swizzled chunk per kk ---
    int wm = wv >> 1, wn = wv & 1, q4 = l >> 4, lr = l & 15;
    int aro[4], bro[4];
#pragma unroll
    for (int mi = 0; mi < 4; mi++) aro[mi] = (wm * 64 + mi * 16 + lr) * 64;
#pragma unroll
    for (int ni = 0; ni < 4; ni++) bro[ni] = 8192 + (wn * 64 + ni * 16 + lr) * 64;
    int sw[2] = { ((q4)     ^ (lr & 7)) * 8,
                  ((4 + q4) ^ (lr & 7)) * 8 };

    floatx4 zz = {0.f, 0.f, 0.f, 0.f};
    floatx4 acc[4][4];
#pragma unroll
    for (int mi = 0; mi < 4; mi++)
#pragma unroll
        for (int ni = 0; ni < 4; ni++) acc[mi][ni] = zz;

    STAGE(0, 0);                       // prologue: tile 0 in flight (8 loads)
    int cur = 0;
    for (int t = 0; t < NTILE; ++t) {
        asm volatile("" ::: "memory");
        __builtin_amdgcn_s_barrier();  // all waves done reading buf cur^1
        asm volatile("" ::: "memory");
        if (t + 1 < NTILE) {
            STAGE(cur ^ 1, t + 1);     // issue next tile (stays in flight)
            asm volatile("s_waitcnt vmcnt(8)" ::: "memory");  // tile t landed
        } else {
            asm volatile("s_waitcnt vmcnt(0)" ::: "memory");
        }
        __builtin_amdgcn_s_barrier();  // tile t visible to all waves
        asm volatile("" ::: "memory");

        const ushort* Lp = &lds[cur * 16384];
#pragma unroll
        for (int kk = 0; kk < 2; ++kk) {
            int so = sw[kk];
            short8 af[4], bfv[4];
#pragma unroll
            for (int ni = 0; ni < 4; ni++) bfv[ni] = *(const short8*)&Lp[bro[ni] + so];
#pragma unroll
            for (int mi = 0; mi < 4; mi++) af[mi] = *(const short8*)&Lp[aro[mi] + so];
#pragma unroll
            for (int mi = 0; mi < 4; mi++)
#pragma unroll
                for (int ni = 0; ni < 4; ni++)
                    acc[mi][ni] = __builtin_amdgcn_mfma_f32_16x16x32_bf16(
                        af[mi], bfv[ni], acc[mi][ni], 0, 0, 0);
        }
        cur ^= 1;
    }
#undef STAGE

    // --- epilogue: C/D col=lane&15, row=quad*4+reg ---
#pragma unroll
    for (int mi = 0; mi < 4; mi++) {
        int rbase = wm * 64 + mi * 16 + q4 * 4;
#pragma unroll
        for (int j = 0; j < 4; j++) {
            int slot2 = mt * 128 + rbase + j;
            if (slot2 >= Ne) continue;   // pad rows: must skip (atomicAdd!)
            int pk2 = tlist[e * T_TOK + slot2];
            int tok2 = pk2 & 0xFFFF, rk2 = (pk2 >> 16) & 1;
#pragma unroll
            for (int ni = 0; ni < 4; ni++) {
                int col = nt * 128 + wn * 64 + ni * 16 + lr;
                float v = acc[mi][ni][j];
                float bc = bias[e * NTOT + col];
                if (MODE == 0) {
                    v = gelu_exact(v + bc);
                    Hout[(size_t)(tok2 * 2 + rk2) * HID + col] = f2bf(v);
                } else {
                    if (kc == 0) v += bc;
                    v *= wlist[e * T_TOK + slot2];
                    atomicAdd(&Yout[(size_t)tok2 * DIM + col], v);
                }
            }
        }
    }
}

// ================= fallback path (proven kernel, ws < 105 MB) ================
template <int MODE>
__global__ __launch_bounds__(256, 2) void moe_gemm(
    const ushort* __restrict__ A, const float* __restrict__ W,
    const float* __restrict__ bias, const int* __restrict__ counts,
    const int* __restrict__ tlist, const float* __restrict__ wlist,
    ushort* __restrict__ Hout, float* __restrict__ Yacc)
{
    constexpr int NTOT = MODE ? DIM : HID;
    constexpr int AROW = MODE ? HID : DIM;
    constexpr int KLEN = MODE ? 2048 : 1024;

    int bx = blockIdx.x;
    int e, mt, nt, kc;
    if (MODE == 0) { e = bx >> 9; mt = (bx >> 5) & 15; nt = bx & 31; kc = 0; }
    else { e = bx >> 8; int r = bx & 255; mt = r >> 4; nt = (r >> 1) & 7; kc = r & 1; }

    int Ne = counts[e];
    if (mt * 128 >= Ne) return;

    size_t wbase = (size_t)e * DIM * HID + (size_t)kc * 2048 * NTOT + (size_t)nt * 128;

    __shared__ ushort ldsA[128 * 40];
    __shared__ ushort ldsB[128 * 36];

    int tid = threadIdx.x;
    int wv = tid >> 6, l = tid & 63;

    const ushort* arowp[2]; int apos[2];
#pragma unroll
    for (int i = 0; i < 2; i++) {
        int idx = i * 256 + tid;
        int r = idx >> 2, p = idx & 3;
        int slot = mt * 128 + r; if (slot >= Ne) slot = Ne - 1;
        int packed = tlist[e * T_TOK + slot];
        int tok = packed & 0xFFFF, rk = (packed >> 16) & 1;
        size_t arow = MODE ? (size_t)(tok * 2 + rk) : (size_t)tok;
        arowp[i] = A + arow * AROW + (MODE ? kc * 2048 : 0) + p * 8;
        apos[i] = r * 40 + p * 8;
    }

    int kp = tid & 15;
    int n8 = tid >> 4;
    size_t boffg = wbase + (size_t)(2 * kp) * NTOT + n8 * 8;

    int wm = wv >> 1, wn = wv & 1;
    int q = l >> 4;
    int aoff[4], boff[4];
#pragma unroll
    for (int mi = 0; mi < 4; mi++)
        aoff[mi] = (wm * 64 + mi * 16 + (l & 15)) * 40 + q * 8;
#pragma unroll
    for (int ni = 0; ni < 4; ni++)
        boff[ni] = (wn * 64 + ni * 16 + (l & 15)) * 36 + q * 8;

    floatx4 zz = {0.f, 0.f, 0.f, 0.f};
    floatx4 acc[4][4];
#pragma unroll
    for (int mi = 0; mi < 4; mi++)
#pragma unroll
        for (int ni = 0; ni < 4; ni++) acc[mi][ni] = zz;

    for (int k0 = 0; k0 < KLEN; k0 += 32) {
        intx4 av[2];
#pragma unroll
        for (int i = 0; i < 2; i++) av[i] = *(const intx4*)(arowp[i] + k0);
        const float* p0 = W + boffg + (size_t)k0 * NTOT;
        const float* p1 = p0 + NTOT;
        floatx4 a0 = *(const floatx4*)(p0);
        floatx4 a1 = *(const floatx4*)(p0 + 4);
        floatx4 b0 = *(const floatx4*)(p1);
        floatx4 b1 = *(const floatx4*)(p1 + 4);
        uint32_t pr[8];
#pragma unroll
        for (int j = 0; j < 8; j++) {
            float va = (j < 4) ? a0[j & 3] : a1[j & 3];
            float vb = (j < 4) ? b0[j & 3] : b1[j & 3];
            pr[j] = (uint32_t)f2bf(va) | ((uint32_t)f2bf(vb) << 16);
        }

        __syncthreads();
#pragma unroll
        for (int i = 0; i < 2; i++) *(intx4*)&ldsA[apos[i]] = av[i];
#pragma unroll
        for (int j = 0; j < 8; j++)
            *(uint32_t*)&ldsB[(n8 * 8 + j) * 36 + 2 * kp] = pr[j];
        __syncthreads();

        short8 af[4], bf[4];
#pragma unroll
        for (int mi = 0; mi < 4; mi++) af[mi] = *(const short8*)&ldsA[aoff[mi]];
#pragma unroll
        for (int ni = 0; ni < 4; ni++) {
            short4v blo = *(const short4v*)&ldsB[boff[ni]];
            short4v bhi = *(const short4v*)&ldsB[boff[ni] + 4];
            bf[ni] = __builtin_shufflevector(blo, bhi, 0, 1, 2, 3, 4, 5, 6, 7);
        }
#pragma unroll
        for (int mi = 0; mi < 4; mi++)
#pragma unroll
            for (int ni = 0; ni < 4; ni++)
                acc[mi][ni] = __builtin_amdgcn_mfma_f32_16x16x32_bf16(
                    af[mi], bf[ni], acc[mi][ni], 0, 0, 0);
    }

#pragma unroll
    for (int mi = 0; mi < 4; mi++) {
        int rbase = wm * 64 + mi * 16 + q * 4;
#pragma unroll
        for (int j = 0; j < 4; j++) {
            int slot = mt * 128 + rbase + j;
            if (slot >= Ne) continue;
            int packed = tlist[e * T_TOK + slot];
            int tok = packed & 0xFFFF, rk = (packed >> 16) & 1;
#pragma unroll
            for (int ni = 0; ni < 4; ni++) {
                int col = nt * 128 + wn * 64 + ni * 16 + (l & 15);
                float v = acc[mi][ni][j];
                float bc = bias[e * NTOT + col];
                if (MODE == 0) {
                    v = gelu_exact(v + bc);
                    Hout[(size_t)(tok * 2 + rk) * HID + col] = f2bf(v);
                } else {
                    if (kc == 0) v += bc;
                    v *= wlist[e * T_TOK + slot];
                    atomicAdd(&Yacc[(size_t)tok * DIM + col], v);
                }
            }
        }
    }
}

__global__ __launch_bounds__(256) void combine_kernel(
    const float* __restrict__ Y, float* __restrict__ out)
{
    int i = (blockIdx.x * 256 + threadIdx.x) * 4;
    *(floatx4*)(out + i) = *(const floatx4*)(Y + i);
}

// ------------------------------------------------- launch
extern "C" void kernel_launch(void* const* d_in, const int* in_sizes, int n_in,
                              void* d_out, int out_size, void* d_ws, size_t ws_size,
                              hipStream_t stream) {
    const float* x  = (const float*)d_in[0];
    const float* Wr = (const float*)d_in[1];
    const float* br = (const float*)d_in[2];
    const float* W1 = (const float*)d_in[3];
    const float* b1 = (const float*)d_in[4];
    const float* W2 = (const float*)d_in[5];
    const float* b2 = (const float*)d_in[6];
    float* out = (float*)d_out;
    char* ws = (char*)d_ws;

    if (ws_size >= 104988928ULL) {
        // layout: counts@0(256B) tlist@256(64K) wlist@65792(64K)
        //         Xb@131328(4MB) Hbuf@4325632(33.55MB) Wt@37880064(67.1MB)
        // Wt holds tiled+swizzled Wt1 for gemm<0>, then Wt2 for gemm<1>.
        int*    counts = (int*)ws;
        int*    tlist  = (int*)(ws + 256);
        float*  wlist  = (float*)(ws + 65792);
        ushort* Xb     = (ushort*)(ws + 131328);
        ushort* Hbuf   = (ushort*)(ws + 4325632);
        ushort* Wt     = (ushort*)(ws + 37880064);

        hipMemsetAsync(counts, 0, 256, stream);
        hipMemsetAsync(out, 0, (size_t)T_TOK * DIM * sizeof(float), stream);
        cast_x_kernel<<<T_TOK * DIM / 2048, 256, 0, stream>>>(x, Xb);
        router_kernel<<<T_TOK / 4, 256, 0, stream>>>(x, Wr, br, counts, tlist, wlist);
        transpose_cast_tiled<<<dim3(DIM / 64, HID / 128, NEXP), 256, 0, stream>>>(
            W1, Wt, DIM, HID);
        moe_gemm4<0><<<NEXP * 16 * 32, 256, 0, stream>>>(
            Xb, Wt, b1, counts, tlist, wlist, Hbuf, nullptr);
        transpose_cast_tiled<<<dim3(HID / 64, DIM / 128, NEXP), 256, 0, stream>>>(
            W2, Wt, HID, DIM);
        moe_gemm4<1><<<NEXP * 16 * 8 * 2, 256, 0, stream>>>(
            Hbuf, Wt, b2, counts, tlist, wlist, nullptr, out);
    } else {
        // fallback: previous proven path (42.07 MB)
        int*    counts = (int*)ws;
        int*    tlist  = (int*)(ws + 256);
        float*  wlist  = (float*)(ws + 256 + 65536);
        ushort* Hbuf   = (ushort*)(ws + 256 + 131072);
        float*  Yacc   = (float*)(ws + 256 + 131072 + 33554432);
        ushort* Xb     = (ushort*)Yacc;

        hipMemsetAsync(counts, 0, 256, stream);
        cast_x_kernel<<<T_TOK * DIM / 2048, 256, 0, stream>>>(x, Xb);
        router_kernel<<<T_TOK / 4, 256, 0, stream>>>(x, Wr, br, counts, tlist, wlist);
        moe_gemm<0><<<NEXP * 16 * 32, 256, 0, stream>>>(Xb, W1, b1, counts, tlist, wlist, Hbuf, nullptr);
        hipMemsetAsync(Yacc, 0, (size_t)T_TOK * DIM * sizeof(float), stream);
        moe_gemm<1><<<NEXP * 16 * 8 * 2, 256, 0, stream>>>(Hbuf, W2, b2, counts, tlist, wlist, nullptr, Yacc);
        combine_kernel<<<out_size / 1024, 256, 0, stream>>>(Yacc, out);
    }
}